// Round 10
// baseline (126.042 us; speedup 1.0000x reference)
//
#include <hip/hip_runtime.h>

typedef float v2f __attribute__((ext_vector_type(2)));

#define NW 64
#define NPL 16           // v2f pairs per lane (32 workers; partner lane ^32 holds the rest)
#define MAX_EVALS 8
#define FREEZE_TOL 7e-3f
// Freeze fires AFTER the step is applied; frozen lanes are superlinear-path,
// post-step residual ~ kappa*st*e_prev << st. absmax pinned at 3.9e-3 (=2^-8,
// the bf16-compare quantum) for tol 1e-3..7e-3 -- tolerance-invariant.

// Worker-split structure (round 10): lane l and lane l^32 share one
// coordinate, 32 workers each -> v[] halves to 32 VGPR -> live set ~75 ->
// (256,6) = 6 waves/SIMD (was 4). Round-8 lesson: the cap (85) must exceed
// the live-set estimate with margin; spill signature = VGPR<50 / FETCH>>262MB.
__global__ __launch_bounds__(256, 6) void damed_median_kernel(
    const float* __restrict__ y, float* __restrict__ out, int D) {
  const int t = blockIdx.x * blockDim.x + threadIdx.x;
  const int sub = (t >> 5) & 1;            // which worker half this lane owns
  const int dcoord = (t >> 6) * 32 + (t & 31);
  const int dc = dcoord < D ? dcoord : D - 1;  // clamp; store is guarded.
  const int wbase = sub * 32;              // first worker of this lane's half

  // 32 worker values as 16 register pairs. y[w][d]: for a fixed pair p the
  // wave's 64 lanes read two 128B-contiguous segments (one per half) -- coalesced.
  v2f v[NPL];
  v2f vmin = {3.4e38f, 3.4e38f}, vmax = {-3.4e38f, -3.4e38f}, sum2 = {0.f, 0.f};
#pragma unroll
  for (int p = 0; p < NPL; ++p) {
    v2f w;
    w.x = y[(size_t)(wbase + 2 * p) * (size_t)D + (size_t)dc];
    w.y = y[(size_t)(wbase + 2 * p + 1) * (size_t)D + (size_t)dc];
    v[p] = w;
    vmin = __builtin_elementwise_min(vmin, w);
    vmax = __builtin_elementwise_max(vmax, w);
    sum2 += w;
  }
  // Combine halves: commutative ops -> both partners get bit-identical results.
  float xl = fminf(vmin.x, vmin.y);
  float xg = fmaxf(vmax.x, vmax.y);
  float sm = sum2.x + sum2.y;
  xl = fminf(xl, __shfl_xor(xl, 32));
  xg = fmaxf(xg, __shfl_xor(xg, 32));
  sm = sm + __shfl_xor(sm, 32);
  float x = sm * (1.0f / NW);
  x = fminf(fmaxf(x, xl), xg);

  // A&S 7.1.27: erf(a) = 1 - q(a)^-4, q = 1 + b1 a + b2 a^2 + b3 a^3 + b4 a^4,
  // |err| <= 5e-4, no exp. Derivative of the approx: 4 q^-5 q'(a), used ONCE
  // (eval A); later evals use the free secant slope.
  const float B1 = 0.278393f, B2 = 0.230389f, B3 = 0.000972f, B4 = 0.078108f;
  const v2f one2 = {1.f, 1.f};
  const v2f Q1 = {B1, B1}, Q2 = {B2, B2}, Q3 = {B3, B3}, Q4 = {B4, B4};
  const v2f P1 = {B1, B1}, P2 = {2 * B2, 2 * B2};
  const v2f P3 = {3 * B3, 3 * B3}, P4 = {4 * B4, 4 * B4};

  // Half-sum value eval over this lane's 32 workers; caller adds partner half.
  auto evalHalf = [&](float xc) -> float {
    v2f fmA = {0.f, 0.f}, fmB = {0.f, 0.f};
    v2f nx = {-xc, -xc};
#pragma unroll
    for (int p = 0; p < NPL; p += 2) {
      v2f tA = v[p] + nx;
      v2f tB = v[p + 1] + nx;
      v2f aA = __builtin_elementwise_max(tA, -tA);
      v2f aB = __builtin_elementwise_max(tB, -tB);
      v2f qA = __builtin_elementwise_fma(aA, Q4, Q3);
      v2f qB = __builtin_elementwise_fma(aB, Q4, Q3);
      qA = __builtin_elementwise_fma(aA, qA, Q2);
      qB = __builtin_elementwise_fma(aB, qB, Q2);
      qA = __builtin_elementwise_fma(aA, qA, Q1);
      qB = __builtin_elementwise_fma(aB, qB, Q1);
      qA = __builtin_elementwise_fma(aA, qA, one2);
      qB = __builtin_elementwise_fma(aB, qB, one2);
      v2f rA, rB;
      rA.x = __builtin_amdgcn_rcpf(qA.x); rA.y = __builtin_amdgcn_rcpf(qA.y);
      rB.x = __builtin_amdgcn_rcpf(qB.x); rB.y = __builtin_amdgcn_rcpf(qB.y);
      rA = rA * rA; rB = rB * rB;   // q^-2
      rA = rA * rA; rB = rB * rB;   // q^-4
      v2f eA = one2 - rA;
      v2f eB = one2 - rB;
      eA.x = __builtin_copysignf(eA.x, tA.x); eA.y = __builtin_copysignf(eA.y, tA.y);
      eB.x = __builtin_copysignf(eB.x, tB.x); eB.y = __builtin_copysignf(eB.y, tB.y);
      fmA += eA; fmB += eB;
    }
    v2f s = fmA + fmB;
    return s.x + s.y;
  };

  // ---- eval A: half value + half analytic derivative, then pair-combine. ----
  float fm0, fd0;
  {
    v2f fmA = {0.f, 0.f}, fmB = {0.f, 0.f}, fdA = {0.f, 0.f}, fdB = {0.f, 0.f};
    v2f nx = {-x, -x};
#pragma unroll
    for (int p = 0; p < NPL; p += 2) {
      v2f tA = v[p] + nx;
      v2f tB = v[p + 1] + nx;
      v2f aA = __builtin_elementwise_max(tA, -tA);
      v2f aB = __builtin_elementwise_max(tB, -tB);
      v2f qA = __builtin_elementwise_fma(aA, Q4, Q3);
      v2f qB = __builtin_elementwise_fma(aB, Q4, Q3);
      qA = __builtin_elementwise_fma(aA, qA, Q2);
      qB = __builtin_elementwise_fma(aB, qB, Q2);
      qA = __builtin_elementwise_fma(aA, qA, Q1);
      qB = __builtin_elementwise_fma(aB, qB, Q1);
      qA = __builtin_elementwise_fma(aA, qA, one2);
      qB = __builtin_elementwise_fma(aB, qB, one2);
      v2f dA = __builtin_elementwise_fma(aA, P4, P3);
      v2f dB = __builtin_elementwise_fma(aB, P4, P3);
      dA = __builtin_elementwise_fma(aA, dA, P2);
      dB = __builtin_elementwise_fma(aB, dB, P2);
      dA = __builtin_elementwise_fma(aA, dA, P1);
      dB = __builtin_elementwise_fma(aB, dB, P1);
      v2f rA, rB;
      rA.x = __builtin_amdgcn_rcpf(qA.x); rA.y = __builtin_amdgcn_rcpf(qA.y);
      rB.x = __builtin_amdgcn_rcpf(qB.x); rB.y = __builtin_amdgcn_rcpf(qB.y);
      v2f r2A = rA * rA, r2B = rB * rB;
      v2f r4A = r2A * r2A, r4B = r2B * r2B;
      v2f r5A = r4A * rA, r5B = r4B * rB;
      fdA = __builtin_elementwise_fma(r5A, dA, fdA);
      fdB = __builtin_elementwise_fma(r5B, dB, fdB);
      v2f eA = one2 - r4A;
      v2f eB = one2 - r4B;
      eA.x = __builtin_copysignf(eA.x, tA.x); eA.y = __builtin_copysignf(eA.y, tA.y);
      eB.x = __builtin_copysignf(eB.x, tB.x); eB.y = __builtin_copysignf(eB.y, tB.y);
      fmA += eA; fmB += eB;
    }
    v2f fm2 = fmA + fmB, fd2 = fdA + fdB;
    float fmh = fm2.x + fm2.y;
    float fdh = fd2.x + fd2.y;
    fm0 = fmh + __shfl_xor(fmh, 32);
    fd0 = 4.0f * (fdh + __shfl_xor(fdh, 32));  // |f'| of the approx, > 0
  }
  // f decreasing: fm>0 => root above x.
  if (fm0 > 0.f) xl = x; else xg = x;
  float xn = x + fm0 * __builtin_amdgcn_rcpf(fd0);
  bool ok = (xn >= xl) && (xn <= xg);  // non-strict (round-1 lesson); NaN->bisect
  float cand = ok ? xn : 0.5f * (xl + xg);
  bool frozen = (__builtin_fabsf(cand - x) <= FREEZE_TOL);
  float xprev = x, fmprev = fm0;
  x = cand;

  // ---- secant refinement: derivative comes free from (xprev, fmprev). ----
#pragma unroll 1
  for (int e = 1; e < MAX_EVALS; ++e) {
    if (__all(frozen)) break;  // wave-uniform, deterministic for fixed input
    float fmh = evalHalf(x);
    float fmc = fmh + __shfl_xor(fmh, 32);  // commutative -> pair-identical
    if (fmc > 0.f) xl = x; else xg = x;
    float xs = x + fmc * (x - xprev) / (fmprev - fmc);  // secant step
    bool ok2 = (xs >= xl) && (xs <= xg);                // NaN/flat -> bisect
    float cand2 = ok2 ? xs : 0.5f * (xl + xg);
    float st = __builtin_fabsf(cand2 - x);
    // fmc==0: x IS the root; freeze (guards exact-zero -> 0/0 -> midpoint hop).
    bool done = (st <= FREEZE_TOL) || (fmc == 0.f);
    float xnew = frozen ? x : cand2;   // frozen lanes do not move
    xprev = frozen ? xprev : x;
    fmprev = frozen ? fmprev : fmc;
    frozen = frozen || done;
    x = xnew;
  }
  if (sub == 0 && dcoord < D) out[dcoord] = x;
}

extern "C" void kernel_launch(void* const* d_in, const int* in_sizes, int n_in,
                              void* d_out, int out_size, void* d_ws, size_t ws_size,
                              hipStream_t stream) {
  const float* y = (const float*)d_in[0];
  float* out = (float*)d_out;
  const int D = out_size;          // 2^21 coordinates
  const int threads = 256;         // 2 threads per coordinate -> 128 coords/block
  const int blocks = (D + 127) / 128;
  damed_median_kernel<<<blocks, threads, 0, stream>>>(y, out, D);
}

// Round 12
// 121.116 us; speedup vs baseline: 1.0407x; 1.0407x over previous
//
#include <hip/hip_runtime.h>

typedef float v2f __attribute__((ext_vector_type(2)));
typedef __fp16 h2v __attribute__((ext_vector_type(2)));  // cvt_pkrtz's return type

#define NW 64
#define NP 32            // worker pairs (one h2v = 2 fp16 workers = 1 VGPR)
#define MAX_EVALS 8
#define FREEZE_TOL 7e-3f
// Freeze fires AFTER the step is applied; frozen lanes are superlinear-path,
// post-step residual ~ kappa*st*e_prev << st. absmax pinned at 3.9e-3 (=2^-8,
// bf16-compare quantum) for tol 1e-3..7e-3 -- tolerance-invariant.

// Storage: v[] packed fp16 (RTZ), 64 workers in 32 VGPRs. fp16 err 4.9e-4 rel
// -> fm RMS err ~3.6e-3 -> root shift ~9e-5: invisible vs the 3.9e-3 floor.
// (256,5): cap ~96-102 vs live ~80 -- margin, unlike round 8 (live 112 -> 3x
// spill cliff: VGPR 32, FETCH 773MB). Round-10 pair-split regressed (shfl +
// duplicated solve, no occupancy step) -- single thread per coord restored.
__global__ __launch_bounds__(256, 5) void damed_median_kernel(
    const float* __restrict__ y, float* __restrict__ out, int D) {
  int d = blockIdx.x * blockDim.x + threadIdx.x;
  if (d >= D) return;

  // Load 64 workers (coalesced: lane i -> coord i), reduce min/max/sum in
  // f32, pack to fp16 pairs for residency.
  h2v v[NP];
  v2f vmin = {3.4e38f, 3.4e38f}, vmax = {-3.4e38f, -3.4e38f}, sum2 = {0.f, 0.f};
#pragma unroll
  for (int p = 0; p < NP; ++p) {
    v2f w;
    w.x = y[(size_t)(2 * p) * (size_t)D + (size_t)d];
    w.y = y[(size_t)(2 * p + 1) * (size_t)D + (size_t)d];
    v[p] = __builtin_amdgcn_cvt_pkrtz(w.x, w.y);  // 1 VGPR / pair
    vmin = __builtin_elementwise_min(vmin, w);
    vmax = __builtin_elementwise_max(vmax, w);
    sum2 += w;
  }
  float xl = fminf(vmin.x, vmin.y);
  float xg = fmaxf(vmax.x, vmax.y);
  float x = (sum2.x + sum2.y) * (1.0f / NW);
  x = fminf(fmaxf(x, xl), xg);

  // A&S 7.1.27: erf(a) = 1 - q(a)^-4, q = 1 + b1 a + b2 a^2 + b3 a^3 + b4 a^4,
  // |err| <= 5e-4, no exp. Derivative of the approx: 4 q^-5 q'(a), used ONCE
  // (eval A); later evals use the free secant slope.
  const float B1 = 0.278393f, B2 = 0.230389f, B3 = 0.000972f, B4 = 0.078108f;
  const v2f one2 = {1.f, 1.f};
  const v2f Q1 = {B1, B1}, Q2 = {B2, B2}, Q3 = {B3, B3}, Q4 = {B4, B4};
  const v2f P1 = {B1, B1}, P2 = {2 * B2, 2 * B2};
  const v2f P3 = {3 * B3, 3 * B3}, P4 = {4 * B4, 4 * B4};

  // Unpack fp16 pair -> f32 v2f (2x v_cvt_f32_f16).
  auto up = [](h2v h) -> v2f {
    v2f r; r.x = (float)h.x; r.y = (float)h.y; return r;
  };

  // Value-only eval: fm(xc) = sum_w erf(v_w - xc); 2x2-way split chains.
  auto evalF = [&](float xc) -> float {
    v2f fmA = {0.f, 0.f}, fmB = {0.f, 0.f};
    v2f nx = {-xc, -xc};
#pragma unroll
    for (int p = 0; p < NP; p += 2) {
      v2f tA = up(v[p]) + nx;
      v2f tB = up(v[p + 1]) + nx;
      v2f aA = __builtin_elementwise_max(tA, -tA);
      v2f aB = __builtin_elementwise_max(tB, -tB);
      v2f qA = __builtin_elementwise_fma(aA, Q4, Q3);
      v2f qB = __builtin_elementwise_fma(aB, Q4, Q3);
      qA = __builtin_elementwise_fma(aA, qA, Q2);
      qB = __builtin_elementwise_fma(aB, qB, Q2);
      qA = __builtin_elementwise_fma(aA, qA, Q1);
      qB = __builtin_elementwise_fma(aB, qB, Q1);
      qA = __builtin_elementwise_fma(aA, qA, one2);
      qB = __builtin_elementwise_fma(aB, qB, one2);
      v2f rA, rB;
      rA.x = __builtin_amdgcn_rcpf(qA.x); rA.y = __builtin_amdgcn_rcpf(qA.y);
      rB.x = __builtin_amdgcn_rcpf(qB.x); rB.y = __builtin_amdgcn_rcpf(qB.y);
      rA = rA * rA; rB = rB * rB;   // q^-2
      rA = rA * rA; rB = rB * rB;   // q^-4
      v2f eA = one2 - rA;
      v2f eB = one2 - rB;
      eA.x = __builtin_copysignf(eA.x, tA.x); eA.y = __builtin_copysignf(eA.y, tA.y);
      eB.x = __builtin_copysignf(eB.x, tB.x); eB.y = __builtin_copysignf(eB.y, tB.y);
      fmA += eA; fmB += eB;
    }
    v2f s = fmA + fmB;
    return s.x + s.y;
  };

  // ---- eval A: value + analytic derivative -> one true Newton step. ----
  float fm0, fd0;
  {
    v2f fmA = {0.f, 0.f}, fmB = {0.f, 0.f}, fdA = {0.f, 0.f}, fdB = {0.f, 0.f};
    v2f nx = {-x, -x};
#pragma unroll
    for (int p = 0; p < NP; p += 2) {
      v2f tA = up(v[p]) + nx;
      v2f tB = up(v[p + 1]) + nx;
      v2f aA = __builtin_elementwise_max(tA, -tA);
      v2f aB = __builtin_elementwise_max(tB, -tB);
      v2f qA = __builtin_elementwise_fma(aA, Q4, Q3);
      v2f qB = __builtin_elementwise_fma(aB, Q4, Q3);
      qA = __builtin_elementwise_fma(aA, qA, Q2);
      qB = __builtin_elementwise_fma(aB, qB, Q2);
      qA = __builtin_elementwise_fma(aA, qA, Q1);
      qB = __builtin_elementwise_fma(aB, qB, Q1);
      qA = __builtin_elementwise_fma(aA, qA, one2);
      qB = __builtin_elementwise_fma(aB, qB, one2);
      v2f dA = __builtin_elementwise_fma(aA, P4, P3);
      v2f dB = __builtin_elementwise_fma(aB, P4, P3);
      dA = __builtin_elementwise_fma(aA, dA, P2);
      dB = __builtin_elementwise_fma(aB, dB, P2);
      dA = __builtin_elementwise_fma(aA, dA, P1);
      dB = __builtin_elementwise_fma(aB, dB, P1);
      v2f rA, rB;
      rA.x = __builtin_amdgcn_rcpf(qA.x); rA.y = __builtin_amdgcn_rcpf(qA.y);
      rB.x = __builtin_amdgcn_rcpf(qB.x); rB.y = __builtin_amdgcn_rcpf(qB.y);
      v2f r2A = rA * rA, r2B = rB * rB;
      v2f r4A = r2A * r2A, r4B = r2B * r2B;
      v2f r5A = r4A * rA, r5B = r4B * rB;
      fdA = __builtin_elementwise_fma(r5A, dA, fdA);
      fdB = __builtin_elementwise_fma(r5B, dB, fdB);
      v2f eA = one2 - r4A;
      v2f eB = one2 - r4B;
      eA.x = __builtin_copysignf(eA.x, tA.x); eA.y = __builtin_copysignf(eA.y, tA.y);
      eB.x = __builtin_copysignf(eB.x, tB.x); eB.y = __builtin_copysignf(eB.y, tB.y);
      fmA += eA; fmB += eB;
    }
    v2f fm2 = fmA + fmB, fd2 = fdA + fdB;
    fm0 = fm2.x + fm2.y;
    fd0 = 4.0f * (fd2.x + fd2.y);  // |f'| of the approx, strictly > 0
  }
  // f decreasing: fm>0 => root above x.
  if (fm0 > 0.f) xl = x; else xg = x;
  float xn = x + fm0 * __builtin_amdgcn_rcpf(fd0);
  bool ok = (xn >= xl) && (xn <= xg);  // non-strict (round-1 lesson); NaN->bisect
  float cand = ok ? xn : 0.5f * (xl + xg);
  bool frozen = (__builtin_fabsf(cand - x) <= FREEZE_TOL);
  float xprev = x, fmprev = fm0;
  x = cand;

  // ---- secant refinement: derivative comes free from (xprev, fmprev). ----
#pragma unroll 1
  for (int e = 1; e < MAX_EVALS; ++e) {
    if (__all(frozen)) break;  // wave-uniform, deterministic for fixed input
    float fmc = evalF(x);
    if (fmc > 0.f) xl = x; else xg = x;
    float xs = x + fmc * (x - xprev) / (fmprev - fmc);  // secant step
    bool ok2 = (xs >= xl) && (xs <= xg);                // NaN/flat -> bisect
    float cand2 = ok2 ? xs : 0.5f * (xl + xg);
    float st = __builtin_fabsf(cand2 - x);
    // fmc==0: x IS the root; freeze (guards exact-zero -> 0/0 -> midpoint hop).
    bool done = (st <= FREEZE_TOL) || (fmc == 0.f);
    float xnew = frozen ? x : cand2;   // frozen lanes do not move
    xprev = frozen ? xprev : x;
    fmprev = frozen ? fmprev : fmc;
    frozen = frozen || done;
    x = xnew;
  }
  out[d] = x;
}

extern "C" void kernel_launch(void* const* d_in, const int* in_sizes, int n_in,
                              void* d_out, int out_size, void* d_ws, size_t ws_size,
                              hipStream_t stream) {
  const float* y = (const float*)d_in[0];
  float* out = (float*)d_out;
  const int D = out_size;  // 2^21 coordinates
  const int threads = 256;
  const int blocks = (D + threads - 1) / threads;
  damed_median_kernel<<<blocks, threads, 0, stream>>>(y, out, D);
}